// Round 4
// baseline (170.171 us; speedup 1.0000x reference)
//
#include <hip/hip_runtime.h>
#include <math.h>

// Problem constants (reference: x [8,2,224,224] f32, weights [1,4] f32)
#define BATCH 8
#define H     224
#define W     224
#define NH    223
#define NW    223
#define PIXB  (H * W)          // 50176 floats per channel per batch
#define NPB   (2 * H * W)      // 100352 floats per batch
#define N4    (NPB / 4)        // 25088 float4 per batch
#define PER_B (NH * NW)        // 49729 output positions per batch
#define GBX   196              // blocks per batch; 196*128 f4 == N4 exactly
#define F4PB  (N4 / GBX)       // 128 float4 slice per block
#define PI_F  3.14159265358979323846f

// Module globals: NOT the harness workspace, so never poisoned. g_cnt is
// monotonic across graph replays: epoch = old/GBX, target = (epoch+1)*GBX.
// Every partial slot is fully rewritten each iteration before the counter
// release, so no per-iteration reset is needed.
__device__ unsigned g_cnt[BATCH];
__device__ float    g_pmin[BATCH][GBX];
__device__ float    g_pmax[BATCH][GBX];

// Single kernel, grid (GBX, BATCH) = 1568 blocks x 256 threads.
// __launch_bounds__(256,8): 8 waves/EU -> 8 blocks/CU -> capacity 2048 >= 1568,
// so all blocks are co-resident and the counter spin cannot deadlock.
__global__ __launch_bounds__(256, 8) void fused_quanv(
        const float* __restrict__ x, const float* __restrict__ wts,
        float* __restrict__ out) {
    const int b   = blockIdx.y;
    const int cb  = blockIdx.x;
    const int tid = threadIdx.x;

    __shared__ float smin[4], smax[4], sred[2];

    // ---- Phase A: this block's 2KB slice min/max (threads 0..127, 1 f4 each)
    float lmin = INFINITY, lmax = -INFINITY;
    if (tid < F4PB) {
        float4 v = ((const float4*)(x + (size_t)b * NPB))[cb * F4PB + tid];
        lmin = fminf(fminf(v.x, v.y), fminf(v.z, v.w));
        lmax = fmaxf(fmaxf(v.x, v.y), fmaxf(v.z, v.w));
    }
    #pragma unroll
    for (int off = 32; off > 0; off >>= 1) {
        lmin = fminf(lmin, __shfl_down(lmin, off, 64));
        lmax = fmaxf(lmax, __shfl_down(lmax, off, 64));
    }
    const int wid = tid >> 6;
    if ((tid & 63) == 0) { smin[wid] = lmin; smax[wid] = lmax; }
    __syncthreads();
    if (tid == 0) {
        lmin = fminf(fminf(smin[0], smin[1]), fminf(smin[2], smin[3]));
        lmax = fmaxf(fmaxf(smax[0], smax[1]), fmaxf(smax[2], smax[3]));
        __hip_atomic_store(&g_pmin[b][cb], lmin, __ATOMIC_RELAXED,
                           __HIP_MEMORY_SCOPE_AGENT);
        __hip_atomic_store(&g_pmax[b][cb], lmax, __ATOMIC_RELAXED,
                           __HIP_MEMORY_SCOPE_AGENT);
    }

    // ---- Phase B: issue phase-2 pixel loads now; latency hides under spin.
    const int  r   = cb * 256 + tid;        // blocks 0..194 cover all positions
    const bool act = r < PER_B;
    float pa0 = 0.f, pa1 = 0.f, pa2 = 0.f, pa3 = 0.f;
    float pb0 = 0.f, pb1 = 0.f, pb2 = 0.f, pb3 = 0.f;
    if (act) {
        const int i = r / NW;
        const int j = r - i * NW;
        const float* c0 = x + (size_t)b * NPB + i * W + j;   // ch0 -> RX angles
        const float* c1 = c0 + PIXB;                         // ch1 -> RY angles
        pa0 = c0[0]; pa1 = c0[1]; pa2 = c0[W]; pa3 = c0[W + 1];
        pb0 = c1[0]; pb1 = c1[1]; pb2 = c1[W]; pb3 = c1[W + 1];
    }

    // ---- Phase C: release this block's contribution; spin for the batch.
    if (tid == 0) {
        unsigned old = __hip_atomic_fetch_add(&g_cnt[b], 1u, __ATOMIC_RELEASE,
                                              __HIP_MEMORY_SCOPE_AGENT);
        const unsigned target = (old / GBX + 1u) * GBX;
        while (__hip_atomic_load(&g_cnt[b], __ATOMIC_ACQUIRE,
                                 __HIP_MEMORY_SCOPE_AGENT) < target)
            __builtin_amdgcn_s_sleep(2);
    }
    __syncthreads();

    // ---- Phase D: reduce the 196 partials (agent-scope loads bypass L1).
    float pm = INFINITY, px = -INFINITY;
    if (tid < GBX) {
        pm = __hip_atomic_load(&g_pmin[b][tid], __ATOMIC_RELAXED,
                               __HIP_MEMORY_SCOPE_AGENT);
        px = __hip_atomic_load(&g_pmax[b][tid], __ATOMIC_RELAXED,
                               __HIP_MEMORY_SCOPE_AGENT);
    }
    #pragma unroll
    for (int off = 32; off > 0; off >>= 1) {
        pm = fminf(pm, __shfl_down(pm, off, 64));
        px = fmaxf(px, __shfl_down(px, off, 64));
    }
    if ((tid & 63) == 0) { smin[wid] = pm; smax[wid] = px; }
    __syncthreads();
    if (tid == 0) {
        sred[0] = fminf(fminf(smin[0], smin[1]), fminf(smin[2], smin[3]));
        sred[1] = fmaxf(fmaxf(smax[0], smax[1]), fmaxf(smax[2], smax[3]));
    }
    __syncthreads();
    const float gmin  = sred[0];
    const float scale = PI_F / (sred[1] - gmin + 1e-8f);

    if (!act) return;

    // ---- Phase E: analytic circuit (identical math to the verified baseline)
    // z_q = cos(a_q) cos(b_q) cos(w_q) - sin(a_q) sin(w_q)
    float sw[4], cw[4];
    #pragma unroll
    for (int q = 0; q < 4; ++q) __sincosf(wts[q], &sw[q], &cw[q]);

    float sa0, ca0, sa1, ca1, sa2, ca2, sa3, ca3;
    __sincosf((pa0 - gmin) * scale, &sa0, &ca0);
    __sincosf((pa1 - gmin) * scale, &sa1, &ca1);
    __sincosf((pa2 - gmin) * scale, &sa2, &ca2);
    __sincosf((pa3 - gmin) * scale, &sa3, &ca3);
    const float cb0 = __cosf((pb0 - gmin) * scale);
    const float cb1 = __cosf((pb1 - gmin) * scale);
    const float cb2 = __cosf((pb2 - gmin) * scale);
    const float cb3 = __cosf((pb3 - gmin) * scale);

    const float z0 = ca0 * cb0 * cw[0] - sa0 * sw[0];
    const float z1 = ca1 * cb1 * cw[1] - sa1 * sw[1];
    const float z2 = ca2 * cb2 * cw[2] - sa2 * sw[2];
    const float z3 = ca3 * cb3 * cw[3] - sa3 * sw[3];

    const size_t base = (size_t)b * 4 * PER_B + r;
    const float z01 = z0 * z1;
    out[base]             = z1 * z2 * z3;
    out[base + PER_B]     = z01;
    out[base + 2 * PER_B] = z01 * z2;
    out[base + 3 * PER_B] = z01 * z2 * z3;
}

extern "C" void kernel_launch(void* const* d_in, const int* in_sizes, int n_in,
                              void* d_out, int out_size, void* d_ws, size_t ws_size,
                              hipStream_t stream) {
    const float* x   = (const float*)d_in[0];   // [8,2,224,224] f32
    const float* wts = (const float*)d_in[1];   // [1,4] f32
    float* out = (float*)d_out;                 // [8,4,223,223] f32

    fused_quanv<<<dim3(GBX, BATCH), 256, 0, stream>>>(x, wts, out);
}

// Round 5
// 61.686 us; speedup vs baseline: 2.7587x; 2.7587x over previous
//
#include <hip/hip_runtime.h>
#include <math.h>

// Problem constants (reference: x [8,2,224,224] f32, weights [1,4] f32)
#define BATCH 8
#define CIN   2
#define H     224
#define W     224
#define NH    223
#define NW    223
#define PIXB  (H * W)          // floats per channel per batch = 50176
#define NPB   (CIN * H * W)    // floats per batch = 100352
#define PER_B (NH * NW)        // output positions per batch = 49729
#define NBPB  ((PER_B + 255) / 256)   // blocks per batch in quanv = 195
#define BPB   32               // reduction blocks per batch
#define PI_F  3.14159265358979323846f

// Kernel 1: per-block partial min/max. 32 blocks per batch, 256 threads each.
// No atomics, no init: ws[b*32+cb] = block min, ws[256 + b*32+cb] = block max.
__global__ __launch_bounds__(256) void minmax_kernel(
        const float* __restrict__ x, float* __restrict__ ws) {
    int b  = blockIdx.x / BPB;
    int cb = blockIdx.x % BPB;
    const float4* xb = (const float4*)(x + (size_t)b * NPB);
    const int n4  = NPB / 4;            // 25088 float4 per batch
    const int per = n4 / BPB;           // 784 float4 per block
    float lmin =  INFINITY, lmax = -INFINITY;
    for (int idx = cb * per + threadIdx.x; idx < (cb + 1) * per; idx += 256) {
        float4 v = xb[idx];
        lmin = fminf(lmin, fminf(fminf(v.x, v.y), fminf(v.z, v.w)));
        lmax = fmaxf(lmax, fmaxf(fmaxf(v.x, v.y), fmaxf(v.z, v.w)));
    }
    #pragma unroll
    for (int off = 32; off > 0; off >>= 1) {
        lmin = fminf(lmin, __shfl_down(lmin, off, 64));
        lmax = fmaxf(lmax, __shfl_down(lmax, off, 64));
    }
    __shared__ float smin[4], smax[4];
    int wid = threadIdx.x >> 6;
    if ((threadIdx.x & 63) == 0) { smin[wid] = lmin; smax[wid] = lmax; }
    __syncthreads();
    if (threadIdx.x == 0) {
        #pragma unroll
        for (int i = 1; i < 4; ++i) {
            lmin = fminf(lmin, smin[i]);
            lmax = fmaxf(lmax, smax[i]);
        }
        ws[b * BPB + cb]               = lmin;
        ws[256 + b * BPB + cb]         = lmax;
    }
}

// Kernel 2: analytic 4-qubit circuit per output position.
// z_q = cos(a_q) cos(b_q) cos(w_q) - sin(a_q) sin(w_q)
// out[b,0] = z1 z2 z3; out[b,1] = z0 z1; out[b,2] = z0 z1 z2; out[b,3] = z0 z1 z2 z3
// Grid: (NBPB, BATCH). b = blockIdx.y (block-uniform). First 32 lanes reduce
// the 32 partials for this batch, broadcast via LDS.
__global__ __launch_bounds__(256) void quanv_kernel(
        const float* __restrict__ x, const float* __restrict__ wts,
        const float* __restrict__ ws, float* __restrict__ out) {
    int b = blockIdx.y;
    __shared__ float sred[2];
    if (threadIdx.x < 32) {
        float mn = ws[b * BPB + threadIdx.x];
        float mx = ws[256 + b * BPB + threadIdx.x];
        #pragma unroll
        for (int off = 16; off > 0; off >>= 1) {
            mn = fminf(mn, __shfl_xor(mn, off, 32));
            mx = fmaxf(mx, __shfl_xor(mx, off, 32));
        }
        if (threadIdx.x == 0) { sred[0] = mn; sred[1] = mx; }
    }
    __syncthreads();
    float gmin  = sred[0];
    float scale = PI_F / (sred[1] - gmin + 1e-8f);

    int r = blockIdx.x * 256 + threadIdx.x;
    if (r >= PER_B) return;
    int i = r / NW;
    int j = r - i * NW;

    const float* c0 = x + (size_t)b * NPB + (size_t)i * W + j;
    const float* c1 = c0 + PIXB;

    float z[4];
    #pragma unroll
    for (int q = 0; q < 4; ++q) {
        int kh = q >> 1, kw = q & 1;
        float pa = c0[kh * W + kw];     // channel 0 -> RX angle a_q
        float pb = c1[kh * W + kw];     // channel 1 -> RY angle b_q
        float a  = (pa - gmin) * scale;
        float bb = (pb - gmin) * scale;
        float sa, ca;
        __sincosf(a, &sa, &ca);
        float cb = __cosf(bb);
        float sw, cw;
        __sincosf(wts[q], &sw, &cw);
        z[q] = ca * cb * cw - sa * sw;
    }

    size_t base = (size_t)b * 4 * PER_B + r;
    float z01 = z[0] * z[1];
    out[base]             = z[1] * z[2] * z[3];
    out[base + PER_B]     = z01;
    out[base + 2 * PER_B] = z01 * z[2];
    out[base + 3 * PER_B] = z01 * z[2] * z[3];
}

extern "C" void kernel_launch(void* const* d_in, const int* in_sizes, int n_in,
                              void* d_out, int out_size, void* d_ws, size_t ws_size,
                              hipStream_t stream) {
    const float* x   = (const float*)d_in[0];   // [8,2,224,224] f32
    const float* wts = (const float*)d_in[1];   // [1,4] f32
    float* out = (float*)d_out;                 // [8,4,223,223] f32
    float* ws  = (float*)d_ws;

    minmax_kernel<<<BATCH * BPB, 256, 0, stream>>>(x, ws);
    quanv_kernel<<<dim3(NBPB, BATCH), 256, 0, stream>>>(x, wts, ws, out);
}